// Round 6
// baseline (99.848 us; speedup 1.0000x reference)
//
#include <hip/hip_runtime.h>

// Problem constants (match reference)
#define S    2048
#define H    16
#define ROWS 32                  // rows per block
#define TPB  256
#define TILES_PER_H (S / ROWS)   // 64
#define MSTRIDE 4096             // padded length of per-head merged vector
#define PREP_SPLIT 4             // blocks per head in prep
#define NCHUNK 520               // f32x4 chunks staged per block (2080 floats)

typedef float f32x4 __attribute__((ext_vector_type(4)));

// out[bh, i, j] = e1[i-j, h] if i>=j else e2[j-i-1, h],  h = bh % 16.
// Reversed merged vector per head:
//   M[h][v] = e1[S-1-v, h]  for v <= S-1
//           = e2[v-S,   h]  for S <= v <= 2S-2, else 0
// then out[i, j] = M[h][(S-1) - i + j]  (row i reads M forward from S-1-i).

// Prep: 64 blocks (4 per head) for gather parallelism; latency-bound.
__global__ __launch_bounds__(TPB) void relpos_prep(
    const float* __restrict__ e1,   // (S, H)
    const float* __restrict__ e2,   // (S-1, H)
    float* __restrict__ M)          // (H, MSTRIDE)
{
    const int h    = blockIdx.x >> 2;            // / PREP_SPLIT
    const int part = blockIdx.x & (PREP_SPLIT - 1);
    float* Mh = M + (size_t)h * MSTRIDE;
    const int v0 = part * (MSTRIDE / PREP_SPLIT);
    const int v1 = v0 + (MSTRIDE / PREP_SPLIT);
    for (int v = v0 + (int)threadIdx.x; v < v1; v += TPB) {
        float val = 0.0f;
        if (v <= S - 1)          val = e1[(S - 1 - v) * H + h];
        else if (v <= 2 * S - 2) val = e2[(v - S) * H + h];
        Mh[v] = val;
    }
}

// Main: stage the block's window span into LDS (8.3 KB, coalesced), then
// pure monotone store stream fed from LDS. Read traffic to L2/HBM ~0.
__global__ __launch_bounds__(TPB) void relpos_main(
    const float* __restrict__ M,    // (H, MSTRIDE) in ws
    float* __restrict__ out)        // (2H, S, S)
{
    __shared__ __align__(16) f32x4 L4[NCHUNK + 8];

    const int tile = blockIdx.x & (TILES_PER_H - 1);
    const int bh   = blockIdx.x >> 6;            // 0..31
    const int h    = bh & (H - 1);
    const int tid  = threadIdx.x;

    const int ibase = tile * ROWS;
    const float* Mh = M + (size_t)h * MSTRIDE;
    float* const o  = out + (size_t)bh * S * S + (size_t)ibase * S;

    // Block needs M[h][2016-ibase .. 4095-ibase] = 2080 floats = 520 chunks.
    const f32x4* M4 = (const f32x4*)&Mh[2016 - ibase];
    for (int c = tid; c < NCHUNK; c += TPB)      // 2-3 coalesced iterations
        L4[c] = M4[c];
    __syncthreads();

    // Thread's half0 window: floats L[4*tid .. 4*tid+35] = chunks tid..tid+8.
    // Half1 (+1024 floats): chunks tid+256 .. tid+264.
    f32x4 w4[18];
    #pragma unroll
    for (int c = 0; c < 9; ++c) w4[c]     = L4[tid + c];
    #pragma unroll
    for (int c = 0; c < 9; ++c) w4[9 + c] = L4[tid + 256 + c];

    const int j0 = tid * 4;
#define W0(t) w4[(t) >> 2][(t) & 3]
#define W1(t) w4[9 + ((t) >> 2)][(t) & 3]
    #pragma unroll
    for (int r = 0; r < ROWS; ++r) {
        f32x4 a, b;
        a.x = W0(31 - r); a.y = W0(32 - r); a.z = W0(33 - r); a.w = W0(34 - r);
        b.x = W1(31 - r); b.y = W1(32 - r); b.z = W1(33 - r); b.w = W1(34 - r);
        *(f32x4*)(o + (size_t)r * S + j0)        = a;
        *(f32x4*)(o + (size_t)r * S + j0 + 1024) = b;
    }
#undef W0
#undef W1
}

extern "C" void kernel_launch(void* const* d_in, const int* in_sizes, int n_in,
                              void* d_out, int out_size, void* d_ws, size_t ws_size,
                              hipStream_t stream) {
    // inputs: d_in[0] = q (unused), d_in[1] = e1 (S*H), d_in[2] = e2 ((S-1)*H)
    const float* e1 = (const float*)d_in[1];
    const float* e2 = (const float*)d_in[2];
    float* out = (float*)d_out;
    float* M   = (float*)d_ws;     // needs H*MSTRIDE*4 = 256 KiB

    relpos_prep<<<H * PREP_SPLIT, TPB, 0, stream>>>(e1, e2, M);
    relpos_main<<<2 * H * TILES_PER_H, TPB, 0, stream>>>(M, out);
}